// Round 18
// baseline (48.887 us; speedup 1.0000x reference)
//
#include <hip/hip_runtime.h>
#include <math.h>

// (N,C,H,W) = (4,19,512,1024), f32 input, scalar f32 output.
// R18: LN-form pass1 — the untested corner: LOW VGPR + MAX TLP.
// Ledger re-read: R9's "7.6 TB/s steady stream" was an L2-resident re-read
// artifact (per-XCD working set ~1.8MB < 4MB L2), not a reachable fresh
// stream. Fresh reads never beat ~4.2 TB/s in ANY fat-register config
// (VGPR>=128, 8-16 waves/CU). LN/RMSNorm-class kernels (82-86% of 6.3TB/s)
// use tiny-VGPR grid-stride forms at 8 waves/SIMD. This is that form:
// 2048 blocks x 256 thr x 2 iters x 2px; per iter a 4-deep STATIC register
// ring over the 19 channels (consume c, reload c+4 into the same slot) ->
// 4 loads in flight/thread, ~35 VGPR, 32 waves/CU.
#define NC 19
#define NN 4
#define HH 512
#define WW 1024
#define NBLK 2048            // 2048 blocks * 256 thr * 2 iters * 2 px = Np
#define ITERS 2
#define NREP 32              // LDS accumulator replicas (rep = tid & 31)
#define COLS (2 * NC)        // 19 ssum cols + 19 hist cols
#define CSTRIDE 2048         // column stride in ws (== NBLK)

typedef float floatx2 __attribute__((ext_vector_type(2)));

__global__ __launch_bounds__(256) void msiw_pass1(const float* __restrict__ x,
                                                  float* __restrict__ ws) {
    __shared__ float s_acc[2][NREP][NC];   // [0]=ssum, [1]=count (float, exact)
    const int tid = threadIdx.x;

    for (int i = tid; i < 2 * NREP * NC; i += 256) (&s_acc[0][0][0])[i] = 0.0f;
    __syncthreads();

    const size_t cs = (size_t)HH * WW;     // channel stride (elements)
    const int rep = tid & (NREP - 1);      // <=2-way same-address alias (free)

    #pragma unroll
    for (int it = 0; it < ITERS; ++it) {
        const int u    = (blockIdx.x * ITERS + it) * 256 + tid;  // float2-unit
        const int w2   = u & 511;              // W/2 = 512
        const int rest = u >> 9;
        const int h    = rest & 511;
        const int n    = rest >> 9;
        const float* base = x + ((size_t)(n * NC) * HH + h) * WW + (size_t)w2 * 2;

        // 4-deep register ring over channels: consume c, reload c+4.
        floatx2 b0 = *reinterpret_cast<const floatx2*>(base);
        floatx2 b1 = *reinterpret_cast<const floatx2*>(base + cs);
        floatx2 b2 = *reinterpret_cast<const floatx2*>(base + 2 * cs);
        floatx2 b3 = *reinterpret_cast<const floatx2*>(base + 3 * cs);
        asm volatile("" ::: "memory");     // all 4 preloads issued before use

        float Z0, Z1, Q0, Q1, m0, m1;
        int   p0, p1;

        #define STEP(c, B)                                                    \
        {                                                                     \
            const float x0 = B.x, x1 = B.y;                                   \
            const float e0 = __expf(x0), e1 = __expf(x1);                     \
            if ((c) == 0) {                                                   \
                Z0 = e0; Z1 = e1; Q0 = e0 * e0; Q1 = e1 * e1;                 \
                m0 = x0; m1 = x1; p0 = 0; p1 = 0;                             \
            } else {                                                          \
                Z0 += e0; Z1 += e1;                                           \
                Q0 = fmaf(e0, e0, Q0); Q1 = fmaf(e1, e1, Q1);                 \
                if (x0 > m0) { m0 = x0; p0 = (c); }                           \
                if (x1 > m1) { m1 = x1; p1 = (c); }                           \
            }                                                                 \
            if ((c) + 4 < NC)                                                 \
                B = *reinterpret_cast<const floatx2*>(base + (size_t)((c) + 4) * cs); \
        }

        STEP(0,  b0) STEP(1,  b1) STEP(2,  b2) STEP(3,  b3)
        STEP(4,  b0) STEP(5,  b1) STEP(6,  b2) STEP(7,  b3)
        STEP(8,  b0) STEP(9,  b1) STEP(10, b2) STEP(11, b3)
        STEP(12, b0) STEP(13, b1) STEP(14, b2) STEP(15, b3)
        STEP(16, b0) STEP(17, b1) STEP(18, b2)
        #undef STEP

        atomicAdd(&s_acc[0][rep][p0], Q0 / (Z0 * Z0));
        atomicAdd(&s_acc[1][rep][p0], 1.0f);
        atomicAdd(&s_acc[0][rep][p1], Q1 / (Z1 * Z1));
        atomicAdd(&s_acc[1][rep][p1], 1.0f);
    }

    __syncthreads();
    // Flush 38 per-block partials, column-major: ws[col*NBLK + block].
    // Kernel boundary provides the device-scope release (no fence needed).
    if (tid < COLS) {
        const int a = (tid < NC) ? 0 : 1;
        const int c = (tid < NC) ? tid : (tid - NC);
        float acc = 0.0f;
        #pragma unroll
        for (int rp = 0; rp < NREP; ++rp) acc += s_acc[a][rp][c];
        ws[(size_t)tid * CSTRIDE + blockIdx.x] = acc;
    }
}

// 16 waves: wave w reduces columns w, w+16, w+32; float4 batched loads.
__global__ __launch_bounds__(1024) void msiw_pass2(const float* __restrict__ ws,
                                                   float* __restrict__ out) {
    __shared__ float s_col[COLS];
    const int tid  = threadIdx.x;
    const int wv   = tid >> 6;       // 0..15
    const int lane = tid & 63;

    for (int col = wv; col < COLS; col += 16) {
        const float4* q = reinterpret_cast<const float4*>(ws + (size_t)col * CSTRIDE);
        float4 a[8];
        #pragma unroll
        for (int i = 0; i < 8; ++i) a[i] = q[lane + i * 64];   // 512 float4 = 2048 f
        float acc = 0.0f;
        #pragma unroll
        for (int i = 0; i < 8; ++i) acc += (a[i].x + a[i].y) + (a[i].z + a[i].w);
        #pragma unroll
        for (int off = 32; off > 0; off >>= 1) acc += __shfl_down(acc, off);
        if (lane == 0) s_col[col] = acc;
    }
    __syncthreads();

    if (tid == 0) {
        const double np_pow = pow((double)NN * HH * WW, 0.8);   // Np^(1-iw)
        double total = 0.0;
        for (int c = 0; c < NC; ++c) {
            double den = pow((double)s_col[NC + c], 0.2) * np_pow;
            if (den < 1.0) den = 1.0;
            total += (double)s_col[c] / den;
        }
        out[0] = (float)(-total / (double)(NN * NC));
    }
}

extern "C" void kernel_launch(void* const* d_in, const int* in_sizes, int n_in,
                              void* d_out, int out_size, void* d_ws, size_t ws_size,
                              hipStream_t stream) {
    const float* x = (const float*)d_in[0];
    float* ws = (float*)d_ws;                 // 38 cols * 2048 floats = 311 KB
    float* out = (float*)d_out;

    msiw_pass1<<<NBLK, 256, 0, stream>>>(x, ws);
    msiw_pass2<<<1, 1024, 0, stream>>>(ws, out);
}